// Round 11
// baseline (228.605 us; speedup 1.0000x reference)
//
#include <hip/hip_runtime.h>
#include <math.h>

#define NPIX (480*640)
#define MDIM 960
#define MPIX (MDIM*MDIM)
#define PACK_M 307201u
#define CNT_STRIDE 32   // one 128B line per bin (atomic contention spread)

// ws layout (u32/f32 units from base)
#define SCAL_OFF 0        // f32[80]: [0..3] pose-derived, ks at 16/32/48/64 (separate lines)
#define OFFS_OFF 80       // u32[10001]
#define SM_OFF   10084    // f32[70000]: 7 planes * 10000
#define PACK_OFF 80084    // u32[NPIX]
#define POS_OFF  387284   // f32[4*NPIX]; byte offset % 16 == 0
#define FEAT_OFF 1616084  // f32[4*NPIX]; byte offset % 16 == 0
// cnt (u32, stride 32, 10000 bins = 1.28MB) ALIASES the start of pos:
// it is fully consumed by scan_pose before scatter writes pos.

// output layout (floats)
#define OUT_FPMAP 0
#define OUT_MAP   10000
#define OUT_POSE  (10000 + 9*MPIX)

typedef float __attribute__((ext_vector_type(4))) f32x4;
__device__ __forceinline__ f32x4 ntload4(const float* p) {
    return __builtin_nontemporal_load((const f32x4*)p);
}
__device__ __forceinline__ void ntstore4(float* p, f32x4 v) {
    __builtin_nontemporal_store(v, (f32x4*)p);
}

// ---------------- count (1 px/thread, bins spread 1 line apart) ----------------
__global__ __launch_bounds__(256) void count_kernel(const float* __restrict__ obs,
                                                    unsigned* __restrict__ cnt,
                                                    unsigned* __restrict__ pack,
                                                    float fcam) {
    int p = blockIdx.x*256 + threadIdx.x;          // 0..307199
    int i = p / 640, j = p - i*640;
    float d = obs[3*NPIX + p];
    float X = ((float)j - 319.5f) * d / fcam + 250.0f;
    float Z = ((float)(479 - i) - 239.5f) * d / fcam + 88.0f;
    float xs = ((X/5.0f - 50.0f)/100.0f)*2.0f;
    float ys = ((d/5.0f - 50.0f)/100.0f)*2.0f;
    float zs = ((Z/5.0f - 32.0f)/80.0f)*2.0f;
    float pos0 = (xs*100.0f)/2.0f + 50.0f;
    float pos1 = (ys*100.0f)/2.0f + 50.0f;
    float pos2 = (zs*80.0f)/2.0f + 40.0f;
    int bx = (int)floorf(pos0), by = (int)floorf(pos1), bz = (int)floorf(pos2);
    unsigned pk = 0xFFFFFFFFu;
    if (bx >= 0 && bx <= 99 && by >= 0 && by <= 99 && bz >= 0 && bz <= 79) {
        unsigned b = (unsigned)(bx*100 + by);
        unsigned rank = atomicAdd(&cnt[b*CNT_STRIDE], 1u);
        pk = b * PACK_M + rank;
    }
    pack[p] = pk;
}

// ---------------- scan (256 threads, one WG) + pose fused; zeroes ks slots ----------------
__global__ __launch_bounds__(256) void scan_pose_kernel(const unsigned* __restrict__ cnt,
                                                        unsigned* __restrict__ offs,
                                                        const float* pose_obs,
                                                        const float* poses_last,
                                                        float* scal, float* out_pose) {
    int tid = threadIdx.x;
    int lane = tid & 63, wave = tid >> 6;
    // zero the ks atomicMax targets (scatter, which runs next, maxes into them)
    if (tid < 4) scal[16*(tid+1)] = 0.0f;
    unsigned lc[40];
    unsigned sum = 0;
    #pragma unroll
    for (int q = 0; q < 40; q++) {
        int idx = tid*40 + q;
        lc[q] = (idx < 10000) ? cnt[idx*CNT_STRIDE] : 0u;
        sum += lc[q];
    }
    unsigned incl = sum;
    #pragma unroll
    for (int off = 1; off < 64; off <<= 1) {
        unsigned u = (unsigned)__shfl_up((int)incl, off, 64);
        if (lane >= off) incl += u;
    }
    __shared__ unsigned wtot[4];
    if (lane == 63) wtot[wave] = incl;
    __syncthreads();
    unsigned pre = 0;
    for (int w = 0; w < wave; w++) pre += wtot[w];
    unsigned excl = pre + incl - sum;
    unsigned run = excl;
    #pragma unroll
    for (int q = 0; q < 40; q++) {
        int idx = tid*40 + q;
        if (idx < 10000) { offs[idx] = run; run += lc[q]; }
    }
    if (tid == 255) {
        offs[10000] = excl;   // == grand total (threads 250..255 contribute 0)
        const float DEGc = 57.29577951308232f;
        float th = poses_last[2] / DEGc;
        float s = sinf(th), c = cosf(th);
        float ny = poses_last[1] + pose_obs[0]*s + pose_obs[1]*c;
        float nx = poses_last[0] + pose_obs[0]*c - pose_obs[1]*s;
        float nt = poses_last[2] + pose_obs[2]*DEGc;
        nt = fmodf(nt - 180.0f, 360.0f) + 180.0f;
        nt = fmodf(nt + 180.0f, 360.0f) - 180.0f;
        out_pose[0] = nx; out_pose[1] = ny; out_pose[2] = nt;
        out_pose[3] = nx; out_pose[4] = ny; out_pose[5] = nt;
        float sx = -((nx*100.0f)/5.0f - 480.0f)/480.0f;
        float sy = -((ny*100.0f)/5.0f - 480.0f)/480.0f;
        float sth = ((90.0f - nt) * 3.14159265358979323846f) / 180.0f;
        scal[0] = cosf(sth);
        scal[1] = sinf(sth);
        scal[2] = sx;
        scal[3] = sy;
    }
}

// ---------------- scatter (atomic-free slot write, 1 px/thread) + ks ----------------
__global__ __launch_bounds__(256) void scatter_kernel(const float* __restrict__ obs,
                                                      const unsigned* __restrict__ offs,
                                                      const unsigned* __restrict__ pack,
                                                      float4* __restrict__ pos,
                                                      float4* __restrict__ feat,
                                                      float* scal, float fcam) {
    int p = blockIdx.x*256 + threadIdx.x;
    int i = p / 640, j = p - i*640;
    unsigned pk = pack[p];
    float d  = obs[3*NPIX + p];
    float f1 = obs[4*NPIX + p];
    float f2 = obs[5*NPIX + p];
    float f3 = obs[6*NPIX + p];
    float f4 = obs[7*NPIX + p];
    float f5 = obs[8*NPIX + p];
    if (pk != 0xFFFFFFFFu) {
        unsigned b = pk / PACK_M;
        unsigned rank = pk - b * PACK_M;
        unsigned k = offs[b] + rank;
        float X = ((float)j - 319.5f) * d / fcam + 250.0f;
        float Z = ((float)(479 - i) - 239.5f) * d / fcam + 88.0f;
        float xs = ((X/5.0f - 50.0f)/100.0f)*2.0f;
        float ys = ((d/5.0f - 50.0f)/100.0f)*2.0f;
        float zs = ((Z/5.0f - 32.0f)/80.0f)*2.0f;
        float pos0 = (xs*100.0f)/2.0f + 50.0f;
        float pos1 = (ys*100.0f)/2.0f + 50.0f;
        float pos2 = (zs*80.0f)/2.0f + 40.0f;
        pos[k]  = make_float4(pos0, pos1, pos2, f1);
        feat[k] = make_float4(f2, f3, f4, f5);
    }
    // ks channel maxima (obs values nonnegative), block-level reduce
    float m0 = f1, m1 = f2, m2 = f3, m3 = f4;
    #pragma unroll
    for (int off = 32; off > 0; off >>= 1) {
        m0 = fmaxf(m0, __shfl_down(m0, off, 64));
        m1 = fmaxf(m1, __shfl_down(m1, off, 64));
        m2 = fmaxf(m2, __shfl_down(m2, off, 64));
        m3 = fmaxf(m3, __shfl_down(m3, off, 64));
    }
    __shared__ float red[4][4];
    int lane = threadIdx.x & 63, wave = threadIdx.x >> 6;
    if (lane == 0) {
        red[wave][0] = m0; red[wave][1] = m1; red[wave][2] = m2; red[wave][3] = m3;
    }
    __syncthreads();
    if (threadIdx.x < 4) {
        int c = threadIdx.x;
        float m = fmaxf(fmaxf(red[0][c], red[1][c]), fmaxf(red[2][c], red[3][c]));
        atomicMax((int*)&scal[16*(c+1)], __float_as_int(m));  // slots 16/32/48/64: separate lines
    }
}

// ---------------- gather: 5000 WGs; 1 block = 2 columns (x,y0),(x,y0+1); 4 waves split points ----
// vs R10 (block = 1 column): block reads the merged 3-y-bin segments once; every read
// point contributes to >=1 owned column, so per-point visits drop 4 -> 3 (25% fewer
// reads). Fat columns remain 4-way wave-split into private slabs (R10's tail fix).
// feat[k] stays unconditional (overlaps pos[k] latency, R10's chain fix).
__global__ __launch_bounds__(256) void gather_kernel(const float4* __restrict__ pos,
                                                     const float4* __restrict__ feat,
                                                     const unsigned* __restrict__ offs,
                                                     float* __restrict__ sm,
                                                     float* __restrict__ out_fp) {
    int wave = threadIdx.x >> 6, lane = threadIdx.x & 63;
    int x  = blockIdx.x % 100;          // corner-x 0..99
    int y0 = (blockIdx.x / 100) * 2;    // owns columns y0, y0+1
    __shared__ float slabs[4][2*488];   // per-wave private, 2 columns; 488 stride pads banks
    float* za = slabs[wave];
    for (int q = lane; q < 2*488; q += 64) za[q] = 0.0f;
    __syncthreads();
    if (x >= 1) {
        int ylo  = (y0 > 0) ? (y0 - 1) : 0;
        int yend = y0 + 2;              // exclusive bin end; y0<=98 -> <=100 (offs[·*100+100] valid)
        unsigned s0 = offs[(x-1)*100 + ylo];
        unsigned e0 = offs[(x-1)*100 + yend];
        unsigned s1 = offs[x*100 + ylo];
        unsigned e1 = offs[x*100 + yend];
        unsigned n0 = e0 - s0, n = n0 + (e1 - s1);
        float xf = (float)x;
        for (unsigned idx = threadIdx.x; idx < n; idx += 256) {
            unsigned k = (idx < n0) ? (s0 + idx) : (s1 + idx - n0);
            float4 a  = pos[k];
            float4 q2 = feat[k];        // unconditional: overlaps with pos load
            // weights replicate reference order: ((1*(1-|d0|))*(1-|d1|))*(1-|d2|)
            float w0 = 1.0f - fabsf(a.x - xf);
            float bzf = floorf(a.z);
            int cy0i = (int)floorf(a.y);
            #pragma unroll
            for (int tt = 0; tt <= 1; tt++) {
                int cy = cy0i + tt;
                if (cy <= 0 || cy >= 100) continue;        // reference safe mask
                if (cy < y0 || cy > y0 + 1) continue;      // owned by this block?
                float w1 = 1.0f - fabsf(a.y - (float)cy);
                float w01 = w0 * w1;
                float* zc = za + (cy - y0) * 488;
                #pragma unroll
                for (int c2 = 0; c2 <= 1; c2++) {
                    float p2 = bzf + (float)c2;
                    if (!(p2 > 0.0f && p2 < 80.0f)) continue;
                    float w = w01 * (1.0f - fabsf(a.z - p2));
                    int zi = (int)p2;
                    int zb = zi * 6;
                    atomicAdd(&zc[zb + 0], w);
                    if (zi >= 13 && zi < 25) {
                        atomicAdd(&zc[zb + 1], w*a.w);
                        atomicAdd(&zc[zb + 2], w*q2.x);
                        atomicAdd(&zc[zb + 3], w*q2.y);
                        atomicAdd(&zc[zb + 4], w*q2.z);
                        atomicAdd(&zc[zb + 5], w*q2.w);
                    }
                }
            }
        }
    }
    __syncthreads();
    // combine the 4 per-wave slabs (pad entries are zero; summing them is harmless)
    for (int q = threadIdx.x; q < 2*488; q += 256) {
        slabs[0][q] = slabs[0][q] + slabs[1][q] + slabs[2][q] + slabs[3][q];
    }
    __syncthreads();
    if (wave < 2) {
        // per-z round, then column sums (exact: summands are small integers)
        const float* zc = &slabs[0][wave*488];   // column y0+wave
        int z = lane;                  // z in [0,64); [64,80) folded by lanes 0..15
        float r0 = rintf(zc[z*6 + 0]);
        float all0 = r0;
        if (lane < 16) all0 += rintf(zc[(z + 64)*6 + 0]);
        bool inb = (z >= 13 && z < 25);
        float a0 = inb ? r0 : 0.0f;
        float a1 = inb ? rintf(zc[z*6 + 1]) : 0.0f;
        float a2 = inb ? rintf(zc[z*6 + 2]) : 0.0f;
        float a3 = inb ? rintf(zc[z*6 + 3]) : 0.0f;
        float a4 = inb ? rintf(zc[z*6 + 4]) : 0.0f;
        float a5 = inb ? rintf(zc[z*6 + 5]) : 0.0f;
        #pragma unroll
        for (int off = 32; off > 0; off >>= 1) {
            all0 += __shfl_down(all0, off, 64);
            a0 += __shfl_down(a0, off, 64);
            a1 += __shfl_down(a1, off, 64);
            a2 += __shfl_down(a2, off, 64);
            a3 += __shfl_down(a3, off, 64);
            a4 += __shfl_down(a4, off, 64);
            a5 += __shfl_down(a5, off, 64);
        }
        if (lane == 0) {
            int t = (y0 + wave)*100 + x;
            float fp = fminf(a0, 1.0f);
            float ex = fminf(all0, 1.0f);
            sm[0*10000 + t] = fp;
            sm[1*10000 + t] = ex;
            sm[2*10000 + t] = fminf(a1/5.0f, 1.0f);
            sm[3*10000 + t] = fminf(a2/5.0f, 1.0f);
            sm[4*10000 + t] = fminf(a3/5.0f, 1.0f);
            sm[5*10000 + t] = fminf(a4/5.0f, 1.0f);
            sm[6*10000 + t] = fminf(a5/5.0f, 1.0f);
            out_fp[t] = fp;
        }
    }
}

// bilinear sample of the (implicit, mostly-zero) agent_view at normalized coords
__device__ __forceinline__ void sample_agent(float gxv, float gyv,
                                             float ct, float sn,
                                             const float* __restrict__ sm,
                                             float rot[7]) {
    float u = ct*gxv - sn*gyv;
    float v = sn*gxv + ct*gyv;
    float xim = ((u + 1.0f)*0.5f)*959.0f;
    float yim = ((v + 1.0f)*0.5f)*959.0f;
    float x0 = floorf(xim), y0 = floorf(yim);
    #pragma unroll
    for (int ty = 0; ty <= 1; ty++) {
        float yy = y0 + (float)ty;
        if (yy < 480.0f || yy >= 580.0f) continue;   // region rows [480,580)
        float wy = 1.0f - fabsf(yim - yy);
        int yi = (int)yy - 480;
        #pragma unroll
        for (int tx = 0; tx <= 1; tx++) {
            float xx = x0 + (float)tx;
            if (xx < 430.0f || xx >= 530.0f) continue;  // region cols [430,530)
            float w = (1.0f - fabsf(xim - xx)) * wy;
            int o = yi*100 + ((int)xx - 430);
            #pragma unroll
            for (int k = 0; k < 7; k++) rot[k] += sm[k*10000 + o] * w;
        }
    }
}

__device__ __forceinline__ void pixel_ts(float xim, float yim, float ct, float sn,
                                         const float* __restrict__ sm, float ts[7]) {
    const float step = 2.0f/959.0f;
    float x0 = floorf(xim), y0 = floorf(yim);
    #pragma unroll
    for (int ty = 0; ty <= 1; ty++) {
        float yy = y0 + (float)ty;
        if (yy < 0.0f || yy > 959.0f) continue;
        float wy = 1.0f - fabsf(yim - yy);
        #pragma unroll
        for (int tx = 0; tx <= 1; tx++) {
            float xx = x0 + (float)tx;
            if (xx < 0.0f || xx > 959.0f) continue;
            float w = (1.0f - fabsf(xim - xx)) * wy;
            float rot[7] = {0,0,0,0,0,0,0};
            float gx1 = xx*step - 1.0f;
            float gy1 = yy*step - 1.0f;
            sample_agent(gx1, gy1, ct, sn, sm, rot);
            #pragma unroll
            for (int k = 0; k < 7; k++) ts[k] += rot[k]*w;
        }
    }
}

// ---------------- final: 2700 WGs, 3-way channel split (3x memory-level parallelism) ----
// The all-zero streaming path was latency-bound at 900 blocks (3.5 blocks/CU,
// ~1.6TB/s). Each third of the grid handles 3 of the 9 channels for the same pixels;
// pixel_ts is recomputed per third only for the ~1.6% active pixels.
__global__ __launch_bounds__(256) void final_kernel(const float* __restrict__ maps_last,
                                                    const float* __restrict__ sm,
                                                    const float* __restrict__ scal,
                                                    float* __restrict__ out_map) {
    int part = blockIdx.x / 900;             // 0,1,2 -> channels 3*part..3*part+2
    int bb   = blockIdx.x - part*900;
    int g = bb*256 + threadIdx.x;            // 0..230399
    int p = g*4;
    int y = p / MDIM, xp = p - y*MDIM;       // 4 pixels share a row (960%4==0)
    int c0 = part*3;
    float ct = scal[0], sn = scal[1], sx = scal[2], sy = scal[3];
    const float step = 2.0f/959.0f;
    float gyv = (float)y*step - 1.0f;
    float v = gyv + sy;
    float yim = ((v + 1.0f)*0.5f)*959.0f;
    float gyc = yim*step - 1.0f;
    float xims[4];
    bool act[4];
    bool any = false;
    #pragma unroll
    for (int q = 0; q < 4; q++) {
        float gxv = (float)(xp+q)*step - 1.0f;
        float u = gxv + sx;
        float xim = ((u + 1.0f)*0.5f)*959.0f;
        xims[q] = xim;
        // Early reject: rotation is an isometry; the 4 translation taps lie
        // within sqrt(2) px of the rotated center; >1.5 px outside the active
        // window (rows (479,580), cols (429,530)) -> every sample exactly 0.
        float gxc = xim*step - 1.0f;
        float uc = ct*gxc - sn*gyc;
        float vc = sn*gxc + ct*gyc;
        float xc2 = ((uc + 1.0f)*0.5f)*959.0f;
        float yc2 = ((vc + 1.0f)*0.5f)*959.0f;
        bool a = (xc2 > 427.5f) && (xc2 < 531.5f) && (yc2 > 477.5f) && (yc2 < 581.5f);
        act[q] = a;
        any = any || a;
    }
    if (!any) {
        // ts == 0 exactly for all 4 pixels: channels -> max(ml, 0); pure stream, NT.
        #pragma unroll
        for (int c = c0; c < c0+3; c++) {
            f32x4 ml = ntload4(maps_last + c*MPIX + p);
            f32x4 o;
            o.x = fmaxf(ml.x, 0.0f); o.y = fmaxf(ml.y, 0.0f);
            o.z = fmaxf(ml.z, 0.0f); o.w = fmaxf(ml.w, 0.0f);
            ntstore4(out_map + c*MPIX + p, o);
        }
        return;
    }
    float ks[4] = {scal[16], scal[32], scal[48], scal[64]};
    #pragma unroll
    for (int q = 0; q < 4; q++) {
        int o = p + q;
        float ts[7] = {0,0,0,0,0,0,0};
        if (act[q]) pixel_ts(xims[q], yim, ct, sn, sm, ts);
        #pragma unroll
        for (int c = c0; c < c0+3; c++) {
            float ml = maps_last[c*MPIX + o];
            float tv;
            if (c == 0) tv = ts[0];
            else if (c == 1) tv = ts[1];
            else if (c == 2 || c == 3) tv = 0.0f;
            else if (c == 8) tv = ts[6];
            else { float t = ts[c-2]; tv = (t > 0.0f) ? ks[c-4] : t; }
            out_map[c*MPIX + o] = fmaxf(ml, tv);
        }
    }
}

extern "C" void kernel_launch(void* const* d_in, const int* in_sizes, int n_in,
                              void* d_out, int out_size, void* d_ws, size_t ws_size,
                              hipStream_t stream) {
    const float* obs        = (const float*)d_in[0];
    const float* pose_obs   = (const float*)d_in[1];
    const float* maps_last  = (const float*)d_in[2];
    const float* poses_last = (const float*)d_in[3];
    float* out = (float*)d_out;

    unsigned* ws_u = (unsigned*)d_ws;
    float*    ws_f = (float*)d_ws;
    float*    scal = ws_f + SCAL_OFF;
    unsigned* offs = ws_u + OFFS_OFF;
    float*    sm   = ws_f + SM_OFF;
    unsigned* pack = ws_u + PACK_OFF;
    float4*   pos  = (float4*)(ws_f + POS_OFF);
    float4*   feat = (float4*)(ws_f + FEAT_OFF);
    unsigned* cnt  = ws_u + POS_OFF;   // aliases pos head; dead before scatter writes

    // single memset: cnt only (1.28MB; scal ks slots zeroed inside scan_pose)
    hipMemsetAsync(ws_f + POS_OFF, 0, (size_t)10000 * CNT_STRIDE * 4u, stream);

    float fcam = (float)(320.0 / tan(39.5 * M_PI / 180.0));

    count_kernel<<<1200, 256, 0, stream>>>(obs, cnt, pack, fcam);
    scan_pose_kernel<<<1, 256, 0, stream>>>(cnt, offs, pose_obs, poses_last,
                                            scal, out + OUT_POSE);
    scatter_kernel<<<1200, 256, 0, stream>>>(obs, offs, pack, pos, feat, scal, fcam);
    gather_kernel<<<5000, 256, 0, stream>>>(pos, feat, offs, sm, out + OUT_FPMAP);
    final_kernel<<<2700, 256, 0, stream>>>(maps_last, sm, scal, out + OUT_MAP);
}